// Round 6
// baseline (137.111 us; speedup 1.0000x reference)
//
#include <hip/hip_runtime.h>
#include <stdint.h>

// Problem constants (B, C1, C2, Co, H, W) = (4, 128, 128, 128, 64, 64)
#define B_    4
#define CIN   256
#define CO    128
#define NPOS  4096   // H*W

typedef float  f4      __attribute__((ext_vector_type(4)));
typedef float  f2      __attribute__((ext_vector_type(2)));
typedef float  f32x16  __attribute__((ext_vector_type(16)));
typedef int    int4v   __attribute__((ext_vector_type(4)));
typedef short  short4v __attribute__((ext_vector_type(4)));
typedef short  short8v __attribute__((ext_vector_type(8)));
typedef __bf16 bf16x8  __attribute__((ext_vector_type(8)));

#if __has_builtin(__builtin_amdgcn_exp2f)
#define EXP2(x) __builtin_amdgcn_exp2f(x)
#else
#define EXP2(x) exp2f(x)
#endif

static __device__ __forceinline__ unsigned short f2bf(float f){
  union { float f; unsigned int u; } v; v.f = f;
  unsigned int u = v.u + 0x7FFFu + ((v.u >> 16) & 1u);
  return (unsigned short)(u >> 16);
}
static __device__ __forceinline__ float bf2f(unsigned short h){
  union { unsigned int u; float f; } v; v.u = ((unsigned int)h) << 16;
  return v.f;
}
static __device__ __forceinline__ unsigned int cvt_pk_bf16(float lo, float hi){
  unsigned int r;
  asm("v_cvt_pk_bf16_f32 %0, %1, %2" : "=v"(r) : "v"(lo), "v"(hi));
  return r;
}

// exchange a float with the partner lane (lane ^ 32) via v_permlane32_swap.
static __device__ __forceinline__ void half_swap_pair(float v, float& x, float& y){
  union { float f; int i; } a; a.f = v;
  auto r = __builtin_amdgcn_permlane32_swap(a.i, a.i, false, false);
  union { int i; float f; } o0, o1; o0.i = (int)r[0]; o1.i = (int)r[1];
  x = o0.f; y = o1.f;
}

// async global->LDS, 16B per lane.  LDS dest = uniform base + lane*16 (linear).
static __device__ __forceinline__ void gload_lds16(const void* g, void* lds){
  __builtin_amdgcn_global_load_lds(
      (const __attribute__((address_space(1))) void*)g,
      (__attribute__((address_space(3))) void*)lds, 16, 0, 0);
}

// ---------------------------------------------------------------------------
// Kernel W-convert: one-time fp32 -> bf16 in MFMA A-fragment order.
// ---------------------------------------------------------------------------
__global__ __launch_bounds__(64) void wconv_kernel(
    const float* __restrict__ Wq, const float* __restrict__ Wk,
    const float* __restrict__ Wv, unsigned short* __restrict__ Wf)
{
  int blk = blockIdx.x;              // 0..191 = ob*16 + cs
  int ob = blk >> 4, cs = blk & 15, l = threadIdx.x;
  int mat = ob >> 2, obl = ob & 3;
  const float* W = (mat == 0) ? Wq : ((mat == 1) ? Wk : Wv);
  int o = obl * 32 + (l & 31);
  int c = cs * 16 + (l >> 5) * 8;
  const float* src = W + (size_t)o * 256 + c;
  f4 a = *(const f4*)src, bb = *(const f4*)(src + 4);
  short8v pk;
  #pragma unroll
  for (int j = 0; j < 4; ++j){ pk[j] = (short)f2bf(a[j]); pk[4+j] = (short)f2bf(bb[j]); }
  *(short8v*)(Wf + ((size_t)blk * 64 + l) * 8) = pk;
}

// ---------------------------------------------------------------------------
// Kernel A: QKV projection as bf16 MFMA GEMM (unchanged structure).
// Q scale now folds log2(e) so attention softmax runs in base-2 domain.
// ---------------------------------------------------------------------------
__global__ __launch_bounds__(256) void qkv_kernel(
    const float* __restrict__ dp, const float* __restrict__ df,
    const unsigned short* __restrict__ Wf,
    const float* __restrict__ bq, const float* __restrict__ bk,
    const float* __restrict__ bv,
    unsigned short* __restrict__ Qf, unsigned short* __restrict__ Kf,
    unsigned short* __restrict__ Vf)
{
  __shared__ unsigned int xs4[32 * 128];   // 16 KB: [n][c] bf16 pairs, swizzled

  int t  = threadIdx.x;
  int b  = blockIdx.x >> 7;
  int kt = blockIdx.x & 127;
  int n0 = kt * 32;

  {
    int cp = t & 127, nh = t >> 7;
    int c0 = cp * 2, c1 = c0 + 1;
    const float* s0 = (c0 < 128) ? dp + ((size_t)b*128 + c0) * NPOS
                                 : df + ((size_t)b*128 + (c0-128)) * NPOS;
    const float* s1 = (c1 < 128) ? dp + ((size_t)b*128 + c1) * NPOS
                                 : df + ((size_t)b*128 + (c1-128)) * NPOS;
    f4 x0[4], x1[4];
    #pragma unroll
    for (int i = 0; i < 4; ++i){
      x0[i] = *(const f4*)(s0 + n0 + nh*16 + i*4);
      x1[i] = *(const f4*)(s1 + n0 + nh*16 + i*4);
    }
    #pragma unroll
    for (int i = 0; i < 16; ++i){
      int n = nh * 16 + i;
      unsigned int pk = cvt_pk_bf16(x0[i>>2][i&3], x1[i>>2][i&3]);
      int chunk = (cp >> 2) ^ (n & 7);           // 16B-chunk XOR swizzle
      xs4[n * 128 + chunk * 4 + (cp & 3)] = pk;
    }
  }
  __syncthreads();

  int w = t >> 6, l = t & 63;
  int lo5 = l & 31, h = l >> 5;

  f32x16 acc[3] = {};
  const unsigned short* WfL = Wf + (size_t)l * 8;

  #pragma unroll 4
  for (int cs = 0; cs < 16; ++cs){
    bf16x8 xf = *(const bf16x8*)((const char*)xs4 +
                 (size_t)(lo5 * 512 + (((cs*2 + h) ^ (lo5 & 7)) * 16)));
    #pragma unroll
    for (int i = 0; i < 3; ++i){
      int ob = w * 3 + i;
      bf16x8 wf = *(const bf16x8*)(WfL + ((size_t)ob * 16 + cs) * 512);
      if (ob < 8) acc[i] = __builtin_amdgcn_mfma_f32_32x32x16_bf16(wf, xf, acc[i], 0, 0, 0);
      else        acc[i] = __builtin_amdgcn_mfma_f32_32x32x16_bf16(xf, wf, acc[i], 0, 0, 0);
    }
  }

  // ---- epilogue: bias (+scale for Q), pack bf16, coalesced 8B stores ----
  const float kScale = 0.12751743f;   // log2(e)/sqrt(128)  (base-2 softmax)
  #pragma unroll
  for (int i = 0; i < 3; ++i){
    int ob = w * 3 + i, mat = ob >> 2, obl = ob & 3;
    if (mat < 2){
      const float* bias = (mat == 0) ? bq : bk;
      unsigned short* dst = ((mat == 0) ? Qf : Kf) + (size_t)(b*128 + kt) * 4096;
      #pragma unroll
      for (int r1 = 0; r1 < 4; ++r1){
        f4 b4 = *(const f4*)(bias + obl*32 + r1*8 + h*4);
        float v0 = acc[i][r1*4+0] + b4[0], v1 = acc[i][r1*4+1] + b4[1];
        float v2 = acc[i][r1*4+2] + b4[2], v3 = acc[i][r1*4+3] + b4[3];
        if (mat == 0){ v0 *= kScale; v1 *= kScale; v2 *= kScale; v3 *= kScale; }
        union { unsigned int u[2]; short4v s; } pk;
        pk.u[0] = cvt_pk_bf16(v0, v1); pk.u[1] = cvt_pk_bf16(v2, v3);
        int ci = obl * 2 + (r1 >> 1);
        size_t si = (size_t)ci * 512 + (size_t)(lo5 + 32*(r1 & 1)) * 8 + 4*h;
        *(short4v*)(dst + si) = pk.s;
      }
    } else {
      float bvl = bv[obl * 32 + lo5];
      unsigned short* dst = Vf + ((size_t)(b*128 + kt) * 8 + obl*2) * 512;
      #pragma unroll
      for (int r1 = 0; r1 < 4; ++r1){
        union { unsigned int u[2]; short4v s; } pk;
        pk.u[0] = cvt_pk_bf16(acc[i][r1*4+0] + bvl, acc[i][r1*4+1] + bvl);
        pk.u[1] = cvt_pk_bf16(acc[i][r1*4+2] + bvl, acc[i][r1*4+3] + bvl);
        size_t si = (size_t)(r1 >> 1) * 512 + (size_t)(lo5 + 32*(r1 & 1)) * 8 + 4*h;
        *(short4v*)(dst + si) = pk.s;
      }
    }
  }
}

// ---------------------------------------------------------------------------
// Kernel B: flash attention, 32x32 swapped-QK + LDS-staged shared K/V.
// K/V fragments are identical across the block's 4 waves -> stage ONCE per
// block into LDS via global_load_lds (linear lane order == fragment order),
// double-buffered, one __syncthreads per tile (implicit vmcnt drain).
// TA/L1 traffic drops 4x; reads move to the LDS pipe.  Softmax in exp2 domain.
// grid = B*32*SPLIT blocks, 256 threads.
// ---------------------------------------------------------------------------
__global__ __launch_bounds__(256) void attn_kernel(
    const unsigned short* __restrict__ Qf, const unsigned short* __restrict__ Kf,
    const unsigned short* __restrict__ Vf, float* __restrict__ OP,
    f2* __restrict__ ML, int SPLIT, int CHUNK)
{
  __shared__ __align__(16) unsigned short kv[2][16][512];  // 32 KB: frags 0-7 K, 8-15 V

  int t    = threadIdx.x;
  int s    = blockIdx.x % SPLIT;
  int rest = blockIdx.x / SPLIT;
  int b    = rest >> 5;
  int qb   = rest & 31;
  int w    = t >> 6;
  int l    = t & 63;
  int lq   = l & 31;    // q-row within the 32-tile
  int h    = l >> 5;    // lane half
  int q0   = qb * 128 + w * 32;

  // Q fragments (fragment-order, coalesced), held for the whole kernel
  const unsigned short* QfL = Qf + (size_t)b * (128 * 8 * 512) + (size_t)l * 8;
  size_t qtb = (size_t)(q0 >> 5) * 4096;
  bf16x8 qf[8];
  #pragma unroll
  for (int ci = 0; ci < 8; ++ci) qf[ci] = *(const bf16x8*)(QfL + qtb + ci * 512);

  const unsigned short* KfL = Kf + (size_t)b * (128 * 8 * 512) + (size_t)l * 8;
  const unsigned short* VfL = Vf + (size_t)b * (128 * 8 * 512) + (size_t)l * 8;

  f32x16 oacc[4] = {};                 // 128 o x 32 q per wave
  float m_run = -3.0e38f, l_run = 0.f;

  const int kbeg = s * CHUNK;
  const int NIT  = CHUNK >> 5;
  const int kt0  = kbeg >> 5;

  // prologue: stage tile 0 into buf 0 (each wave stages 4 of 16 fragments)
  {
    size_t tbn = (size_t)kt0 * 4096;
    #pragma unroll
    for (int ff = 0; ff < 4; ++ff){
      int f = w * 4 + ff;
      const unsigned short* g = (f < 8) ? (KfL + tbn + (size_t)f * 512)
                                        : (VfL + tbn + (size_t)(f - 8) * 512);
      gload_lds16(g, &kv[0][f][0]);
    }
  }
  __syncthreads();

  for (int it = 0; it < NIT; ++it){
    int cur = it & 1;

    // stage next tile into the other buffer (in flight until end-of-tile barrier)
    {
      int itn = (it + 1 < NIT) ? it + 1 : 0;   // wraparound stage is harmless
      size_t tbn = (size_t)(kt0 + itn) * 4096;
      #pragma unroll
      for (int ff = 0; ff < 4; ++ff){
        int f = w * 4 + ff;
        const unsigned short* g = (f < 8) ? (KfL + tbn + (size_t)f * 512)
                                          : (VfL + tbn + (size_t)(f - 8) * 512);
        gload_lds16(g, &kv[cur ^ 1][f][0]);
      }
    }

    // K fragments from LDS, QK^T
    bf16x8 kfr[8];
    #pragma unroll
    for (int ci = 0; ci < 8; ++ci) kfr[ci] = *(const bf16x8*)(&kv[cur][ci][l * 8]);
    f32x16 sA = {}, sB = {};
    __builtin_amdgcn_s_setprio(1);
    #pragma unroll
    for (int ci = 0; ci < 4; ++ci){
      sA = __builtin_amdgcn_mfma_f32_32x32x16_bf16(kfr[2*ci],   qf[2*ci],   sA, 0, 0, 0);
      sB = __builtin_amdgcn_mfma_f32_32x32x16_bf16(kfr[2*ci+1], qf[2*ci+1], sB, 0, 0, 0);
    }
    __builtin_amdgcn_s_setprio(0);

    // V fragments (issue early; consumed after softmax)
    bf16x8 vfr[8];
    #pragma unroll
    for (int fi = 0; fi < 8; ++fi) vfr[fi] = *(const bf16x8*)(&kv[cur][8 + fi][l * 8]);

    // online softmax (base-2 domain; defer-max THR=8)
    f32x16 sv = sA + sB;
    float a0_ = fmaxf(fmaxf(sv[0],  sv[1]),  sv[2]);
    float a1_ = fmaxf(fmaxf(sv[3],  sv[4]),  sv[5]);
    float a2_ = fmaxf(fmaxf(sv[6],  sv[7]),  sv[8]);
    float a3_ = fmaxf(fmaxf(sv[9],  sv[10]), sv[11]);
    float a4_ = fmaxf(fmaxf(sv[12], sv[13]), sv[14]);
    float vm  = fmaxf(fmaxf(fmaxf(fmaxf(a0_, a1_), a2_), fmaxf(a3_, a4_)), sv[15]);
    { float xx_, yy_; half_swap_pair(vm, xx_, yy_);
      vm = fmaxf(vm, fmaxf(xx_, yy_)); }
    if (!__all(vm <= m_run + 8.0f)){
      float m_new = fmaxf(m_run, vm);
      float alpha = EXP2(m_run - m_new);
      #pragma unroll
      for (int ob = 0; ob < 4; ++ob){
        #pragma unroll
        for (int i = 0; i < 16; ++i) oacc[ob][i] *= alpha;
      }
      l_run *= alpha;
      m_run = m_new;
    }
    float p[16];
    #pragma unroll
    for (int i = 0; i < 16; ++i) p[i] = EXP2(sv[i] - m_run);
    float t0 = (p[0]  + p[1])  + (p[2]  + p[3]);
    float t1 = (p[4]  + p[5])  + (p[6]  + p[7]);
    float t2 = (p[8]  + p[9])  + (p[10] + p[11]);
    float t3 = (p[12] + p[13]) + (p[14] + p[15]);
    float ts = (t0 + t1) + (t2 + t3);
    { float xx_, yy_; half_swap_pair(ts, xx_, yy_); ts = xx_ + yy_; }
    l_run += ts;

    // pack P -> bf16 fragments (permlane32_swap builds both PV B-operands)
    unsigned int pw[8];
    #pragma unroll
    for (int i = 0; i < 8; ++i) pw[i] = cvt_pk_bf16(p[2*i], p[2*i+1]);
    auto r20  = __builtin_amdgcn_permlane32_swap((int)pw[2], (int)pw[0], false, false);
    auto r31  = __builtin_amdgcn_permlane32_swap((int)pw[3], (int)pw[1], false, false);
    auto r64v = __builtin_amdgcn_permlane32_swap((int)pw[6], (int)pw[4], false, false);
    auto r75  = __builtin_amdgcn_permlane32_swap((int)pw[7], (int)pw[5], false, false);
    union { int4v i4; bf16x8 b; } pb0, pb1;
    pb0.i4 = (int4v){(int)r20[1],  (int)r31[1], (int)r20[0],  (int)r31[0]};
    pb1.i4 = (int4v){(int)r64v[1], (int)r75[1], (int)r64v[0], (int)r75[0]};

    __builtin_amdgcn_s_setprio(1);
    #pragma unroll
    for (int ob = 0; ob < 4; ++ob){
      oacc[ob] = __builtin_amdgcn_mfma_f32_32x32x16_bf16(vfr[2*ob],   pb0.b, oacc[ob], 0, 0, 0);
      oacc[ob] = __builtin_amdgcn_mfma_f32_32x32x16_bf16(vfr[2*ob+1], pb1.b, oacc[ob], 0, 0, 0);
    }
    __builtin_amdgcn_s_setprio(0);

    __syncthreads();   // drains vmcnt (stage complete) + syncs buffer swap
  }

  // store UNDIVIDED partial accumulator + (m,l)   (m,l in base-2 domain)
  float* Ob = OP + (((size_t)b * NPOS + q0 + lq) * SPLIT + s) * 128 + h * 4;
  #pragma unroll
  for (int ob = 0; ob < 4; ++ob){
    #pragma unroll
    for (int rg = 0; rg < 4; ++rg){
      f4 vv;
      vv[0] = oacc[ob][rg*4+0]; vv[1] = oacc[ob][rg*4+1];
      vv[2] = oacc[ob][rg*4+2]; vv[3] = oacc[ob][rg*4+3];
      *(f4*)(Ob + ob * 32 + rg * 8) = vv;
    }
  }
  if (h == 0){
    f2 ml; ml[0] = m_run; ml[1] = l_run;
    ML[((size_t)b * NPOS + q0 + lq) * SPLIT + s] = ml;
  }
}

// ---------------------------------------------------------------------------
// Kernel C: combine split-K partials + gate + residual blend.
// (exp -> exp2: ML is in base-2 domain now.)
// ---------------------------------------------------------------------------
__global__ __launch_bounds__(256) void gate_kernel(
    const float* __restrict__ OP, const f2* __restrict__ ML,
    const float* __restrict__ Wg, const float* __restrict__ bg,
    const float* __restrict__ gamma, const float* __restrict__ dp,
    float* __restrict__ out, int SPLIT)
{
  __shared__ float          oat[128 * 65];   // 33.3 KB  [c][p] combined out_attn
  __shared__ unsigned short gt[128 * 65];    // 16.6 KB  [o][p] gate (bf16)
  __shared__ float          wsm[64 * 8];     // 2 KB     per-row split weights

  int t  = threadIdx.x;
  int b  = blockIdx.x >> 6;
  int n0 = (blockIdx.x & 63) * 64;

  if (t < 64){
    size_t mlb = ((size_t)b * NPOS + n0 + t) * SPLIT;
    float mmax = -3.0e38f;
    for (int sp = 0; sp < SPLIT; ++sp) mmax = fmaxf(mmax, ML[mlb + sp][0]);
    float L = 0.f;
    for (int sp = 0; sp < SPLIT; ++sp) L += ML[mlb + sp][1] * EXP2(ML[mlb + sp][0] - mmax);
    float Linv = 1.0f / L;
    for (int sp = 0; sp < SPLIT; ++sp)
      wsm[t * 8 + sp] = EXP2(ML[mlb + sp][0] - mmax) * Linv;
  }
  __syncthreads();

  #pragma unroll
  for (int i = 0; i < 32; ++i){
    int idx = i * 256 + t;
    int p = idx >> 7, c = idx & 127;
    const float* op = OP + (((size_t)b * NPOS + n0 + p) * SPLIT) * 128 + c;
    float acc = 0.f;
    for (int sp = 0; sp < SPLIT; ++sp) acc += wsm[p * 8 + sp] * op[(size_t)sp * 128];
    oat[c * 65 + p] = acc;
  }
  __syncthreads();

  int o = t & 127, g = t >> 7;
  float bgv = bg[o];
  float acc[32];
  #pragma unroll
  for (int p = 0; p < 32; ++p) acc[p] = bgv;
  for (int c = 0; c < 128; ++c){
    float w = Wg[o * 128 + c];
    const float* xp = &oat[c * 65 + g * 32];
    #pragma unroll
    for (int p = 0; p < 32; ++p) acc[p] += w * xp[p];
  }
  #pragma unroll
  for (int p = 0; p < 32; ++p){
    float gate = 1.0f / (1.0f + __expf(-acc[p]));
    gt[o * 65 + g * 32 + p] = f2bf(gate);
  }
  __syncthreads();

  float gm = gamma[0];
  #pragma unroll
  for (int i = 0; i < 32; ++i){
    int idx = i * 256 + t;
    int oo = idx >> 6, nl = idx & 63;
    float gv = bf2f(gt[oo * 65 + nl]);
    float ov = oat[oo * 65 + nl];
    float rs = dp[((size_t)b * 128 + oo) * NPOS + n0 + nl];
    out[((size_t)b * 128 + oo) * NPOS + n0 + nl] = gm * gv * ov + (1.0f - gv) * rs;
  }
}

// ---------------------------------------------------------------------------
extern "C" void kernel_launch(void* const* d_in, const int* in_sizes, int n_in,
                              void* d_out, int out_size, void* d_ws, size_t ws_size,
                              hipStream_t stream)
{
  (void)in_sizes; (void)n_in; (void)out_size;
  const float* dp    = (const float*)d_in[0];
  const float* df    = (const float*)d_in[1];
  const float* Wq    = (const float*)d_in[2];
  const float* bq    = (const float*)d_in[3];
  const float* Wk    = (const float*)d_in[4];
  const float* bk    = (const float*)d_in[5];
  const float* Wv    = (const float*)d_in[6];
  const float* bv    = (const float*)d_in[7];
  const float* Wg    = (const float*)d_in[8];
  const float* bg    = (const float*)d_in[9];
  const float* gamma = (const float*)d_in[10];

  const size_t qkvBytes = (size_t)3 * B_ * NPOS * 128 * 2;       // 12.6 MB
  const size_t wfBytes  = (size_t)12 * 16 * 64 * 8 * 2;          // 196.6 KB
  int SPLIT = 1;
  for (int cand = 8; cand >= 1; cand >>= 1){
    size_t need = qkvBytes + wfBytes
                + (size_t)B_ * NPOS * cand * 128 * 4              // OP fp32
                + (size_t)B_ * NPOS * cand * 8;                   // ML float2
    if (need <= ws_size){ SPLIT = cand; break; }
  }
  int CHUNK = NPOS / SPLIT;

  unsigned short* Qf = (unsigned short*)d_ws;
  unsigned short* Kf = Qf + (size_t)B_ * NPOS * 128;
  unsigned short* Vf = Kf + (size_t)B_ * NPOS * 128;
  float*          OP = (float*)(Vf + (size_t)B_ * NPOS * 128);
  f2*             ML = (f2*)(OP + (size_t)B_ * NPOS * SPLIT * 128);
  unsigned short* Wf = (unsigned short*)(ML + (size_t)B_ * NPOS * SPLIT);
  float*          out = (float*)d_out;

  wconv_kernel<<<dim3(192), dim3(64), 0, stream>>>(Wq, Wk, Wv, Wf);
  qkv_kernel<<<dim3(B_ * 128), dim3(256), 0, stream>>>(dp, df, Wf, bq, bk, bv, Qf, Kf, Vf);
  attn_kernel<<<dim3(B_ * 32 * SPLIT), dim3(256), 0, stream>>>(Qf, Kf, Vf, OP, ML, SPLIT, CHUNK);
  gate_kernel<<<dim3(B_ * 64), dim3(256), 0, stream>>>(OP, ML, Wg, bg, gamma, dp, out, SPLIT);
}